// Round 4
// baseline (191.536 us; speedup 1.0000x reference)
//
#include <hip/hip_runtime.h>
#include <cstdint>
#include <cstddef>

// GPT-2 attention block: qkv = x@Wa + ba ; causal softmax(QK^T) V ; out = a@Wp + bp
// B=4 S=2048 D=1024 H=16 hd=64. All matmuls in bf16 MFMA (fp32 accum).

using f32x4  = __attribute__((ext_vector_type(4))) float;
using f32x16 = __attribute__((ext_vector_type(16))) float;
using bf8    = __attribute__((ext_vector_type(8))) __bf16;

static __device__ __forceinline__ short f2bf(float f) {
  union { float f; unsigned u; } v; v.f = f;
  unsigned r = v.u + 0x7fffu + ((v.u >> 16) & 1u);  // RNE
  return (short)(r >> 16);
}

static __device__ __forceinline__ bf8 ldbf8(const short* p) { return *(const bf8*)p; }

static __device__ __forceinline__ f32x4 mfma16(bf8 a, bf8 b, f32x4 c) {
  return __builtin_amdgcn_mfma_f32_16x16x32_bf16(a, b, c, 0, 0, 0);
}
static __device__ __forceinline__ f32x16 mfma32(bf8 a, bf8 b, f32x16 c) {
  return __builtin_amdgcn_mfma_f32_32x32x16_bf16(a, b, c, 0, 0, 0);
}

static __device__ __forceinline__ void gload16(const void* g, void* l) {
  __builtin_amdgcn_global_load_lds((const __attribute__((address_space(1))) void*)g,
                                   (__attribute__((address_space(3))) void*)l, 16, 0, 0);
}

static __device__ __forceinline__ unsigned cvtpk(float a, float b) {
  unsigned r;
  asm("v_cvt_pk_bf16_f32 %0, %1, %2" : "=v"(r) : "v"(a), "v"(b));
  return r;
}
static __device__ __forceinline__ void permswap(unsigned& a, unsigned& b) {
  asm("v_permlane32_swap_b32 %0, %1" : "+v"(a), "+v"(b));
}

// vmcnt(N) + raw barrier + compiler memory fence (prevents ds_read hoist above barrier)
#define KWAIT(N) do { asm volatile("s_waitcnt vmcnt(" #N ")" ::: "memory"); \
    __builtin_amdgcn_s_barrier(); asm volatile("" ::: "memory"); } while (0)

// ---------------- cast x (fp32) -> bf16 ----------------
__global__ __launch_bounds__(256) void k_cast(const float* __restrict__ in, short* __restrict__ out) {
  int i = blockIdx.x * 256 + threadIdx.x;
  float4 v = ((const float4*)in)[i];
  short4 o; o.x = f2bf(v.x); o.y = f2bf(v.y); o.z = f2bf(v.z); o.w = f2bf(v.w);
  ((short4*)out)[i] = o;
}

// ---------------- W[K][N] fp32 -> Wt[N][K] bf16 ----------------
__global__ __launch_bounds__(256) void k_transpose(const float* __restrict__ W, short* __restrict__ Wt,
                                                   int K, int N) {
  __shared__ short Ls[64][66];
  int k0 = blockIdx.x * 64, n0 = blockIdx.y * 64;
  int t = threadIdx.x;
#pragma unroll
  for (int p = 0; p < 16; ++p) {
    int idx = p * 256 + t;
    int kk = idx >> 6, nn = idx & 63;
    Ls[kk][nn] = f2bf(W[(size_t)(k0 + kk) * N + n0 + nn]);
  }
  __syncthreads();
#pragma unroll
  for (int p = 0; p < 16; ++p) {
    int idx = p * 256 + t;
    int nn = idx >> 6, kk = idx & 63;
    Wt[(size_t)(n0 + nn) * K + k0 + kk] = Ls[kk][nn];
  }
}

// ---------------- deep-pipelined GEMM: BM=256 BN=128 BK=32, 4 LDS bufs, counted vmcnt ----
// WHICH=0: A=[8192,1024]x Wt[3072,1024] -> scatter Q/K [bh][s][64], V^T [bh][64][2048], bias
// WHICH=1: A=[8192,1024]x Wt[1024,1024] -> fp32 Out + bias
static __device__ __forceinline__ void gemm5_compute(const short* ab, const short* bb,
                                                     const int* aoff, const int* boff,
                                                     f32x4 (&acc)[4][4]) {
  bf8 af[4], bfr[4];
#pragma unroll
  for (int mi = 0; mi < 4; ++mi) af[mi] = ldbf8(ab + aoff[mi]);
#pragma unroll
  for (int ni = 0; ni < 4; ++ni) bfr[ni] = ldbf8(bb + boff[ni]);
  __builtin_amdgcn_s_setprio(1);
#pragma unroll
  for (int mi = 0; mi < 4; ++mi)
#pragma unroll
    for (int ni = 0; ni < 4; ++ni)
      acc[mi][ni] = mfma16(af[mi], bfr[ni], acc[mi][ni]);
  __builtin_amdgcn_s_setprio(0);
}

template <int WHICH>
__global__ __launch_bounds__(512, 2) void k_gemm5(const short* __restrict__ Ag, const short* __restrict__ Bg,
                                                   const float* __restrict__ bias,
                                                   short* __restrict__ Qb, short* __restrict__ Kb,
                                                   short* __restrict__ VbT, float* __restrict__ Out) {
  constexpr int NTN = (WHICH == 0) ? 24 : 8;   // N tiles of 128 (3072 or 1024)
  constexpr int NWG = 32 * NTN;
  __shared__ __align__(16) short As[4][256 * 32];
  __shared__ __align__(16) short Bs[4][128 * 32];
  int bid = blockIdx.x;
  int wg = (bid & 7) * (NWG >> 3) + (bid >> 3);   // bijective XCD swizzle (NWG%8==0)
  int m0 = (wg / NTN) * 256, n0 = (wg % NTN) * 128;
  int t = threadIdx.x, w = t >> 6, l = t & 63;
  // staging: per K-tile, A = 2 gloads (rows w*16.. and 128+w*16..), B = 1 gload.
  // chunk swizzle: stored slot s holds logical chunk s ^ ((row>>1)&3)  (read-side 2-way free)
  int sr = l >> 2;
  int arow0 = w * 16 + sr;
  int arow1 = 128 + w * 16 + sr;
  int brow  = w * 16 + sr;
  const short* aS0 = Ag + (size_t)(m0 + arow0) * 1024 + (((l & 3) ^ ((arow0 >> 1) & 3)) * 8);
  const short* aS1 = Ag + (size_t)(m0 + arow1) * 1024 + (((l & 3) ^ ((arow1 >> 1) & 3)) * 8);
  const short* bS  = Bg + (size_t)(n0 + brow ) * 1024 + (((l & 3) ^ ((brow  >> 1) & 3)) * 8);
  short* aD0 = &As[0][(w * 16) * 32];
  short* aD1 = &As[0][(128 + w * 16) * 32];
  short* bD  = &Bs[0][(w * 16) * 32];
  const int wmB = (w >> 1) * 64, wnB = (w & 1) * 64;   // 4x2 wave grid -> 64x64 per wave
  int aoff[4], boff[4];
#pragma unroll
  for (int mi = 0; mi < 4; ++mi) { int r = wmB + mi * 16 + (l & 15); aoff[mi] = r * 32 + (((l >> 4) ^ ((r >> 1) & 3)) * 8); }
#pragma unroll
  for (int ni = 0; ni < 4; ++ni) { int r = wnB + ni * 16 + (l & 15); boff[ni] = r * 32 + (((l >> 4) ^ ((r >> 1) & 3)) * 8); }
  f32x4 acc[4][4] = {};

#define STAGE5(tt) do { int _b = (tt) & 3; \
    gload16(aS0 + (tt) * 32, aD0 + _b * (256 * 32)); \
    gload16(aS1 + (tt) * 32, aD1 + _b * (256 * 32)); \
    gload16(bS  + (tt) * 32, bD  + _b * (128 * 32)); } while (0)

  // prologue: stage tiles 0,1,2 (9 loads); vmcnt(6) => tile0 landed
  STAGE5(0); STAGE5(1); STAGE5(2);
  KWAIT(6);
  // main: compute t (buf t&3), issue t+3 (buf freed at end of t-1). 32 K-tiles total.
  for (int kt = 0; kt < 29; ++kt) {
    STAGE5(kt + 3);
    gemm5_compute(&As[kt & 3][0], &Bs[kt & 3][0], aoff, boff, acc);
    KWAIT(6);   // outstanding = tiles kt+2,kt+3 (6); tile kt+1 landed
  }
  gemm5_compute(&As[29 & 3][0], &Bs[29 & 3][0], aoff, boff, acc);
  KWAIT(3);
  gemm5_compute(&As[30 & 3][0], &Bs[30 & 3][0], aoff, boff, acc);
  KWAIT(0);
  gemm5_compute(&As[31 & 3][0], &Bs[31 & 3][0], aoff, boff, acc);
#undef STAGE5

  float bv[4];
#pragma unroll
  for (int ni = 0; ni < 4; ++ni) bv[ni] = bias[n0 + wnB + ni * 16 + (l & 15)];
  if constexpr (WHICH == 1) {
#pragma unroll
    for (int mi = 0; mi < 4; ++mi) {
      int gr0 = m0 + wmB + mi * 16 + (l >> 4) * 4;
#pragma unroll
      for (int ni = 0; ni < 4; ++ni) {
        int gc = n0 + wnB + ni * 16 + (l & 15);
#pragma unroll
        for (int r = 0; r < 4; ++r)
          Out[(size_t)(gr0 + r) * 1024 + gc] = acc[mi][ni][r] + bv[ni];
      }
    }
  } else {
#pragma unroll
    for (int mi = 0; mi < 4; ++mi) {
      int gr0 = m0 + wmB + mi * 16 + (l >> 4) * 4;
      int bq = gr0 >> 11, s0 = gr0 & 2047;
#pragma unroll
      for (int ni = 0; ni < 4; ++ni) {
        int gc = n0 + wnB + ni * 16 + (l & 15);
        int which = gc >> 10, rem = gc & 1023;
        int hh = rem >> 6, dd = rem & 63;
        if (which == 2) {
          short4 pk;
          pk.x = f2bf(acc[mi][ni][0] + bv[ni]);
          pk.y = f2bf(acc[mi][ni][1] + bv[ni]);
          pk.z = f2bf(acc[mi][ni][2] + bv[ni]);
          pk.w = f2bf(acc[mi][ni][3] + bv[ni]);
          *(short4*)&VbT[((size_t)((bq * 16 + hh) * 64 + dd)) * 2048 + s0] = pk;
        } else {
          short* dst = which == 0 ? Qb : Kb;
#pragma unroll
          for (int r = 0; r < 4; ++r)
            dst[((size_t)((bq * 16 + hh) * 2048 + (s0 + r))) * 64 + dd] = f2bf(acc[mi][ni][r] + bv[ni]);
        }
      }
    }
  }
}

// ---------------- Flash attention v3: swapped 32x32 MFMA, in-register P ----------------
static __device__ __forceinline__ void stage_kv(const short* __restrict__ Kg, const short* __restrict__ Vg,
                                                short* KsB, short* VsB, int w, int l, int kv0) {
#pragma unroll
  for (int i = 0; i < 2; ++i) {
    int k = i * 64 + w * 8 + (l >> 3);
    int c = (l & 7) ^ (k & 7);
    gload16(Kg + (size_t)(kv0 + k) * 64 + c * 8, KsB + i * 4096 + w * 512);
  }
#pragma unroll
  for (int i = 0; i < 2; ++i) {
    int d = i * 32 + w * 4 + (l >> 4);
    int s = l & 15;
    int c = (s & 8) | ((s & 7) ^ (d & 7));
    gload16(Vg + (size_t)d * 2048 + kv0 + c * 8, VsB + i * 4096 + w * 512);
  }
}

template <bool MASK>
static __device__ __forceinline__ void attn_tile(const short* __restrict__ KsB, const short* __restrict__ VsB,
                                                 const bf8* qf, f32x16* oa, float& lsum,
                                                 int kv0, int qg, int hi, int l31, int l7) {
  bf8 pfr[8];
#pragma unroll
  for (int kb = 0; kb < 4; ++kb) {
    f32x16 sv = {};
#pragma unroll
    for (int dk = 0; dk < 4; ++dk) {
      bf8 kf = ldbf8(&KsB[(32 * kb + l31) * 64 + (((2 * dk + hi) ^ l7) * 8)]);
      sv = mfma32(kf, qf[dk], sv);
    }
    float pe[16];
#pragma unroll
    for (int r = 0; r < 16; ++r) {
      float e = __expf(sv[r]);
      if constexpr (MASK) {
        int kg = kv0 + 32 * kb + ((r & 3) + 8 * (r >> 2) + 4 * hi);
        e = (kg > qg) ? 0.f : e;
      }
      pe[r] = e;
      lsum += e;
    }
#pragma unroll
    for (int rh = 0; rh < 2; ++rh) {
      unsigned a01 = cvtpk(pe[8 * rh + 0], pe[8 * rh + 1]);
      unsigned a23 = cvtpk(pe[8 * rh + 2], pe[8 * rh + 3]);
      unsigned b01 = cvtpk(pe[8 * rh + 4], pe[8 * rh + 5]);
      unsigned b23 = cvtpk(pe[8 * rh + 6], pe[8 * rh + 7]);
      permswap(a01, b01);
      permswap(a23, b23);
      union { unsigned u[4]; bf8 v; } fu;
      fu.u[0] = a01; fu.u[1] = a23; fu.u[2] = b01; fu.u[3] = b23;
      pfr[2 * kb + rh] = fu.v;
    }
  }
#pragma unroll
  for (int db = 0; db < 2; ++db) {
#pragma unroll
    for (int ks = 0; ks < 8; ++ks) {
      int c = 2 * ks + hi;
      bf8 vf = ldbf8(&VsB[(32 * db + l31) * 128 + (((c & 8) | ((c & 7) ^ l7)) * 8)]);
      oa[db] = mfma32(pfr[ks], vf, oa[db]);
    }
  }
}

static __device__ __forceinline__ void attn_writeout(short* __restrict__ A2, const f32x16* oa, float lsum,
                                                     int b, int h, int qw, int hi, int l31) {
  float lf = lsum + __shfl_xor(lsum, 32, 64);
#pragma unroll
  for (int r = 0; r < 16; ++r) {
    int cr = (r & 3) + 8 * (r >> 2) + 4 * hi;
    float li = __shfl(lf, cr, 64);
    float ri = 1.0f / li;
    size_t row = (size_t)(b * 2048 + qw + cr) * 1024 + h * 64 + l31;
#pragma unroll
    for (int db = 0; db < 2; ++db)
      A2[row + 32 * db] = f2bf(oa[db][r] * ri);
  }
}

__global__ __launch_bounds__(512) void k_attn(const short* __restrict__ Q, const short* __restrict__ K,
                                              const short* __restrict__ VT, short* __restrict__ A2) {
  __shared__ __align__(16) short Ks[2][128 * 64];
  __shared__ __align__(16) short Vs[2][64 * 128];
  int bh = blockIdx.x;
  int pr = blockIdx.y;                // 0..3, processes q-tiles (pr, 7-pr): constant 18 KV tiles
  int b = bh >> 4, h = bh & 15;
  int t = threadIdx.x, w = t >> 6, l = t & 63;
  int hi = l >> 5, l31 = l & 31, l7 = l & 7;
  const short* Qg = Q + (size_t)bh * 2048 * 64;
  const short* Kg = K + (size_t)bh * 2048 * 64;
  const short* Vg = VT + (size_t)bh * 64 * 2048;

  int qt0 = pr, qt1 = 7 - pr;
  int nt0 = 2 * (qt0 + 1);
  int total = nt0 + 2 * (qt1 + 1);

  const f32x16 ZERO = {};
  f32x16 oa[2] = {};
  float lsum = 0.f;

  int qw = qt0 * 256 + w * 32;
  int qg = qw + l31;
  bf8 qf[4];
#pragma unroll
  for (int dk = 0; dk < 4; ++dk) qf[dk] = ldbf8(Qg + (size_t)qg * 64 + dk * 16 + hi * 8);

  stage_kv(Kg, Vg, Ks[0], Vs[0], w, l, 0);
  __syncthreads();

  for (int i = 0; i < total; ++i) {
    int buf = i & 1;
    if (i + 1 < total) {
      int tn = (i + 1 >= nt0) ? (i + 1 - nt0) : (i + 1);
      stage_kv(Kg, Vg, Ks[buf ^ 1], Vs[buf ^ 1], w, l, tn * 128);
    }
    int kv0 = ((i >= nt0) ? (i - nt0) : i) * 128;
    if (kv0 <= qw + 31) {
      if (kv0 + 127 > qw) attn_tile<true >(Ks[buf], Vs[buf], qf, oa, lsum, kv0, qg, hi, l31, l7);
      else                attn_tile<false>(Ks[buf], Vs[buf], qf, oa, lsum, kv0, qg, hi, l31, l7);
    }
    if (i == nt0 - 1) {
      attn_writeout(A2, oa, lsum, b, h, qw, hi, l31);
      oa[0] = ZERO; oa[1] = ZERO; lsum = 0.f;
      qw = qt1 * 256 + w * 32;
      qg = qw + l31;
#pragma unroll
      for (int dk = 0; dk < 4; ++dk) qf[dk] = ldbf8(Qg + (size_t)qg * 64 + dk * 16 + hi * 8);
    }
    __syncthreads();
  }
  attn_writeout(A2, oa, lsum, b, h, qw, hi, l31);
}

extern "C" void kernel_launch(void* const* d_in, const int* in_sizes, int n_in,
                              void* d_out, int out_size, void* d_ws, size_t ws_size,
                              hipStream_t stream) {
  const float* x      = (const float*)d_in[0];
  const float* w_attn = (const float*)d_in[1];
  const float* b_attn = (const float*)d_in[2];
  const float* w_proj = (const float*)d_in[3];
  const float* b_proj = (const float*)d_in[4];
  float* out = (float*)d_out;
  char* ws = (char*)d_ws;
  if (ws_size < 92274688u) return;  // need 88 MB scratch
  short* Xb  = (short*)(ws);                 // [8192][1024] bf16
  short* Wta = (short*)(ws + 16777216);      // [3072][1024] bf16 (W^T)
  short* Wtp = (short*)(ws + 23068672);      // [1024][1024] bf16 (W^T)
  short* Qb  = (short*)(ws + 25165824);      // [64 bh][2048][64]
  short* Kb  = (short*)(ws + 41943040);      // [64 bh][2048][64]
  short* VbT = (short*)(ws + 58720256);      // [64 bh][64 d][2048 s]
  short* A2  = (short*)(ws + 75497472);      // [8192][1024] bf16

  hipLaunchKernelGGL(k_cast, dim3(8192), dim3(256), 0, stream, x, Xb);
  hipLaunchKernelGGL(k_transpose, dim3(16, 48), dim3(256), 0, stream, w_attn, Wta, 1024, 3072);
  hipLaunchKernelGGL(k_transpose, dim3(16, 16), dim3(256), 0, stream, w_proj, Wtp, 1024, 1024);
  hipLaunchKernelGGL((k_gemm5<0>), dim3(768), dim3(512), 0, stream, Xb, Wta, b_attn, Qb, Kb, VbT, nullptr);
  hipLaunchKernelGGL(k_attn, dim3(64, 4), dim3(512), 0, stream, Qb, Kb, VbT, A2);
  hipLaunchKernelGGL((k_gemm5<1>), dim3(256), dim3(512), 0, stream, A2, Wtp, b_proj, nullptr, nullptr, nullptr, out);
}

// Round 5
// 178.241 us; speedup vs baseline: 1.0746x; 1.0746x over previous
//
#include <hip/hip_runtime.h>
#include <cstdint>
#include <cstddef>

// GPT-2 attention block: qkv = x@Wa + ba ; causal softmax(QK^T) V ; out = a@Wp + bp
// B=4 S=2048 D=1024 H=16 hd=64. All matmuls in bf16 MFMA (fp32 accum).

using f32x4  = __attribute__((ext_vector_type(4))) float;
using f32x16 = __attribute__((ext_vector_type(16))) float;
using bf8    = __attribute__((ext_vector_type(8))) __bf16;

static __device__ __forceinline__ short f2bf(float f) {
  union { float f; unsigned u; } v; v.f = f;
  unsigned r = v.u + 0x7fffu + ((v.u >> 16) & 1u);  // RNE
  return (short)(r >> 16);
}

static __device__ __forceinline__ bf8 ldbf8(const short* p) { return *(const bf8*)p; }

static __device__ __forceinline__ f32x4 mfma16(bf8 a, bf8 b, f32x4 c) {
  return __builtin_amdgcn_mfma_f32_16x16x32_bf16(a, b, c, 0, 0, 0);
}
static __device__ __forceinline__ f32x16 mfma32(bf8 a, bf8 b, f32x16 c) {
  return __builtin_amdgcn_mfma_f32_32x32x16_bf16(a, b, c, 0, 0, 0);
}

static __device__ __forceinline__ void gload16(const void* g, void* l) {
  __builtin_amdgcn_global_load_lds((const __attribute__((address_space(1))) void*)g,
                                   (__attribute__((address_space(3))) void*)l, 16, 0, 0);
}

static __device__ __forceinline__ unsigned cvtpk(float a, float b) {
  unsigned r;
  asm("v_cvt_pk_bf16_f32 %0, %1, %2" : "=v"(r) : "v"(a), "v"(b));
  return r;
}
static __device__ __forceinline__ void permswap(unsigned& a, unsigned& b) {
  asm("v_permlane32_swap_b32 %0, %1" : "+v"(a), "+v"(b));
}

// vmcnt(N) + raw barrier + compiler memory fence
#define KWAIT(N) do { asm volatile("s_waitcnt vmcnt(" #N ")" ::: "memory"); \
    __builtin_amdgcn_s_barrier(); asm volatile("" ::: "memory"); } while (0)

// ---------------- cast x (fp32) -> bf16 ----------------
__global__ __launch_bounds__(256) void k_cast(const float* __restrict__ in, short* __restrict__ out) {
  int i = blockIdx.x * 256 + threadIdx.x;
  float4 v = ((const float4*)in)[i];
  short4 o; o.x = f2bf(v.x); o.y = f2bf(v.y); o.z = f2bf(v.z); o.w = f2bf(v.w);
  ((short4*)out)[i] = o;
}

// ---------------- W[K][N] fp32 -> Wt[N][K] bf16 ----------------
__global__ __launch_bounds__(256) void k_transpose(const float* __restrict__ W, short* __restrict__ Wt,
                                                   int K, int N) {
  __shared__ short Ls[64][66];
  int k0 = blockIdx.x * 64, n0 = blockIdx.y * 64;
  int t = threadIdx.x;
#pragma unroll
  for (int p = 0; p < 16; ++p) {
    int idx = p * 256 + t;
    int kk = idx >> 6, nn = idx & 63;
    Ls[kk][nn] = f2bf(W[(size_t)(k0 + kk) * N + n0 + nn]);
  }
  __syncthreads();
#pragma unroll
  for (int p = 0; p < 16; ++p) {
    int idx = p * 256 + t;
    int nn = idx >> 6, kk = idx & 63;
    Wt[(size_t)(n0 + nn) * K + k0 + kk] = Ls[kk][nn];
  }
}

// ---------------- GEMM v8: BM=256 BN=128 BK=64, 8 waves (2Mx4N), 2 bufs, 1 barrier/tile ----
// WHICH=0: Xb[8192,1024] x Wta[3072,1024]^T -> Q/K [bh][s][64], V^T [bh][64][2048], +bias
// WHICH=1: A2[8192,1024] x Wtp[1024,1024]^T -> fp32 Out, +bias
static __device__ __forceinline__ void gemm8_compute(const short* __restrict__ Ab,
                                                     const short* __restrict__ Bb,
                                                     const int (&aoff)[8][2], const int (&boff)[2][2],
                                                     f32x4 (&acc)[8][2]) {
  bf8 bfr[2][2];
#pragma unroll
  for (int j = 0; j < 2; ++j)
#pragma unroll
    for (int ks = 0; ks < 2; ++ks)
      bfr[j][ks] = ldbf8(Bb + boff[j][ks]);
#pragma unroll
  for (int mi = 0; mi < 8; ++mi) {
    bf8 a0 = ldbf8(Ab + aoff[mi][0]);
    bf8 a1 = ldbf8(Ab + aoff[mi][1]);
    __builtin_amdgcn_s_setprio(1);
    acc[mi][0] = mfma16(a0, bfr[0][0], acc[mi][0]);
    acc[mi][0] = mfma16(a1, bfr[0][1], acc[mi][0]);
    acc[mi][1] = mfma16(a0, bfr[1][0], acc[mi][1]);
    acc[mi][1] = mfma16(a1, bfr[1][1], acc[mi][1]);
    __builtin_amdgcn_s_setprio(0);
  }
}

template <int WHICH>
__global__ __launch_bounds__(512, 2) void k_gemm8(const short* __restrict__ Ag, const short* __restrict__ Bg,
                                                   const float* __restrict__ bias,
                                                   short* __restrict__ Qb, short* __restrict__ Kb,
                                                   short* __restrict__ VbT, float* __restrict__ Out) {
  constexpr int NTN = (WHICH == 0) ? 24 : 8;     // N/128
  constexpr int NWG = 32 * NTN;
  __shared__ __align__(16) short As[2][256 * 64];
  __shared__ __align__(16) short Bs[2][128 * 64];
  int bid = blockIdx.x;
  int wg = (bid & 7) * (NWG >> 3) + (bid >> 3);  // bijective XCD swizzle (NWG%8==0)
  int m0 = (wg / NTN) * 256, n0 = (wg % NTN) * 128;
  int t = threadIdx.x, w = t >> 6, l = t & 63;
  int wm = w >> 2, wn = w & 3;                   // wave -> 128x32 C sub-tile

  // staging: A = 4 gloads (64 rows each), B = 2 gloads. stored slot s holds logical
  // chunk s ^ (row&7)  => pre-swizzled global source, linear LDS dest (rule 21).
  int srow = w * 8 + (l >> 3);
  int sswz = ((l & 7) ^ (srow & 7)) * 8;
  const short* aSrc = Ag + (size_t)(m0 + srow) * 1024 + sswz;
  const short* bSrc = Bg + (size_t)(n0 + srow) * 1024 + sswz;

  // fragment LDS byte-offsets (shorts), swizzled reads
  int aoff[8][2], boff[2][2];
#pragma unroll
  for (int mi = 0; mi < 8; ++mi)
#pragma unroll
    for (int ks = 0; ks < 2; ++ks) {
      int rr = wm * 128 + mi * 16 + (l & 15);
      aoff[mi][ks] = rr * 64 + (((ks * 4 + (l >> 4)) ^ (rr & 7)) * 8);
    }
#pragma unroll
  for (int j = 0; j < 2; ++j)
#pragma unroll
    for (int ks = 0; ks < 2; ++ks) {
      int rr = wn * 32 + j * 16 + (l & 15);
      boff[j][ks] = rr * 64 + (((ks * 4 + (l >> 4)) ^ (rr & 7)) * 8);
    }
  f32x4 acc[8][2] = {};

#define STAGE8(kt, bf) do { \
    _Pragma("unroll") for (int g = 0; g < 4; ++g) \
      gload16(aSrc + (size_t)g * 65536 + (kt) * 64, &As[bf][g * 4096 + w * 512]); \
    _Pragma("unroll") for (int g = 0; g < 2; ++g) \
      gload16(bSrc + (size_t)g * 65536 + (kt) * 64, &Bs[bf][g * 4096 + w * 512]); \
  } while (0)

  STAGE8(0, 0);
  KWAIT(0);
  for (int kt = 0; kt < 15; ++kt) {
    STAGE8(kt + 1, (kt + 1) & 1);            // buf freed at barrier ending tile kt-1
    gemm8_compute(As[kt & 1], Bs[kt & 1], aoff, boff, acc);
    KWAIT(0);                                // drains loads issued a full tile ago (~free)
  }
  gemm8_compute(As[1], Bs[1], aoff, boff, acc);
#undef STAGE8

  float bv[2];
#pragma unroll
  for (int nj = 0; nj < 2; ++nj) bv[nj] = bias[n0 + wn * 32 + nj * 16 + (l & 15)];
  if constexpr (WHICH == 1) {
#pragma unroll
    for (int mi = 0; mi < 8; ++mi) {
      int gr0 = m0 + wm * 128 + mi * 16 + (l >> 4) * 4;
#pragma unroll
      for (int nj = 0; nj < 2; ++nj) {
        int gc = n0 + wn * 32 + nj * 16 + (l & 15);
#pragma unroll
        for (int r = 0; r < 4; ++r)
          Out[(size_t)(gr0 + r) * 1024 + gc] = acc[mi][nj][r] + bv[nj];
      }
    }
  } else {
#pragma unroll
    for (int mi = 0; mi < 8; ++mi) {
      int gr0 = m0 + wm * 128 + mi * 16 + (l >> 4) * 4;
      int bq = gr0 >> 11, s0 = gr0 & 2047;
#pragma unroll
      for (int nj = 0; nj < 2; ++nj) {
        int gc = n0 + wn * 32 + nj * 16 + (l & 15);
        int which = gc >> 10, rem = gc & 1023;
        int hh = rem >> 6, dd = rem & 63;
        if (which == 2) {
          short4 pk;
          pk.x = f2bf(acc[mi][nj][0] + bv[nj]);
          pk.y = f2bf(acc[mi][nj][1] + bv[nj]);
          pk.z = f2bf(acc[mi][nj][2] + bv[nj]);
          pk.w = f2bf(acc[mi][nj][3] + bv[nj]);
          *(short4*)&VbT[((size_t)((bq * 16 + hh) * 64 + dd)) * 2048 + s0] = pk;
        } else {
          short* dst = which == 0 ? Qb : Kb;
#pragma unroll
          for (int r = 0; r < 4; ++r)
            dst[((size_t)((bq * 16 + hh) * 2048 + (s0 + r))) * 64 + dd] = f2bf(acc[mi][nj][r] + bv[nj]);
        }
      }
    }
  }
}

// ---------------- Flash attention v3: swapped 32x32 MFMA, in-register P ----------------
static __device__ __forceinline__ void stage_kv(const short* __restrict__ Kg, const short* __restrict__ Vg,
                                                short* KsB, short* VsB, int w, int l, int kv0) {
#pragma unroll
  for (int i = 0; i < 2; ++i) {
    int k = i * 64 + w * 8 + (l >> 3);
    int c = (l & 7) ^ (k & 7);
    gload16(Kg + (size_t)(kv0 + k) * 64 + c * 8, KsB + i * 4096 + w * 512);
  }
#pragma unroll
  for (int i = 0; i < 2; ++i) {
    int d = i * 32 + w * 4 + (l >> 4);
    int s = l & 15;
    int c = (s & 8) | ((s & 7) ^ (d & 7));
    gload16(Vg + (size_t)d * 2048 + kv0 + c * 8, VsB + i * 4096 + w * 512);
  }
}

template <bool MASK>
static __device__ __forceinline__ void attn_tile(const short* __restrict__ KsB, const short* __restrict__ VsB,
                                                 const bf8* qf, f32x16* oa, float& lsum,
                                                 int kv0, int qg, int hi, int l31, int l7) {
  bf8 pfr[8];
#pragma unroll
  for (int kb = 0; kb < 4; ++kb) {
    f32x16 sv = {};
#pragma unroll
    for (int dk = 0; dk < 4; ++dk) {
      bf8 kf = ldbf8(&KsB[(32 * kb + l31) * 64 + (((2 * dk + hi) ^ l7) * 8)]);
      sv = mfma32(kf, qf[dk], sv);
    }
    float pe[16];
#pragma unroll
    for (int r = 0; r < 16; ++r) {
      float e = __expf(sv[r]);
      if constexpr (MASK) {
        int kg = kv0 + 32 * kb + ((r & 3) + 8 * (r >> 2) + 4 * hi);
        e = (kg > qg) ? 0.f : e;
      }
      pe[r] = e;
      lsum += e;
    }
#pragma unroll
    for (int rh = 0; rh < 2; ++rh) {
      unsigned a01 = cvtpk(pe[8 * rh + 0], pe[8 * rh + 1]);
      unsigned a23 = cvtpk(pe[8 * rh + 2], pe[8 * rh + 3]);
      unsigned b01 = cvtpk(pe[8 * rh + 4], pe[8 * rh + 5]);
      unsigned b23 = cvtpk(pe[8 * rh + 6], pe[8 * rh + 7]);
      permswap(a01, b01);
      permswap(a23, b23);
      union { unsigned u[4]; bf8 v; } fu;
      fu.u[0] = a01; fu.u[1] = a23; fu.u[2] = b01; fu.u[3] = b23;
      pfr[2 * kb + rh] = fu.v;
    }
  }
#pragma unroll
  for (int db = 0; db < 2; ++db) {
#pragma unroll
    for (int ks = 0; ks < 8; ++ks) {
      int c = 2 * ks + hi;
      bf8 vf = ldbf8(&VsB[(32 * db + l31) * 128 + (((c & 8) | ((c & 7) ^ l7)) * 8)]);
      oa[db] = mfma32(pfr[ks], vf, oa[db]);
    }
  }
}

static __device__ __forceinline__ void attn_writeout(short* __restrict__ A2, const f32x16* oa, float lsum,
                                                     int b, int h, int qw, int hi, int l31) {
  float lf = lsum + __shfl_xor(lsum, 32, 64);
#pragma unroll
  for (int r = 0; r < 16; ++r) {
    int cr = (r & 3) + 8 * (r >> 2) + 4 * hi;
    float li = __shfl(lf, cr, 64);
    float ri = 1.0f / li;
    size_t row = (size_t)(b * 2048 + qw + cr) * 1024 + h * 64 + l31;
#pragma unroll
    for (int db = 0; db < 2; ++db)
      A2[row + 32 * db] = f2bf(oa[db][r] * ri);
  }
}

__global__ __launch_bounds__(512) void k_attn(const short* __restrict__ Q, const short* __restrict__ K,
                                              const short* __restrict__ VT, short* __restrict__ A2) {
  __shared__ __align__(16) short Ks[2][128 * 64];
  __shared__ __align__(16) short Vs[2][64 * 128];
  int bh = blockIdx.x;
  int pr = blockIdx.y;                // 0..3, processes q-tiles (pr, 7-pr): constant 18 KV tiles
  int b = bh >> 4, h = bh & 15;
  int t = threadIdx.x, w = t >> 6, l = t & 63;
  int hi = l >> 5, l31 = l & 31, l7 = l & 7;
  const short* Qg = Q + (size_t)bh * 2048 * 64;
  const short* Kg = K + (size_t)bh * 2048 * 64;
  const short* Vg = VT + (size_t)bh * 64 * 2048;

  int qt0 = pr, qt1 = 7 - pr;
  int nt0 = 2 * (qt0 + 1);
  int total = nt0 + 2 * (qt1 + 1);

  const f32x16 ZERO = {};
  f32x16 oa[2] = {};
  float lsum = 0.f;

  int qw = qt0 * 256 + w * 32;
  int qg = qw + l31;
  bf8 qf[4];
#pragma unroll
  for (int dk = 0; dk < 4; ++dk) qf[dk] = ldbf8(Qg + (size_t)qg * 64 + dk * 16 + hi * 8);

  stage_kv(Kg, Vg, Ks[0], Vs[0], w, l, 0);
  __syncthreads();

  for (int i = 0; i < total; ++i) {
    int buf = i & 1;
    if (i + 1 < total) {
      int tn = (i + 1 >= nt0) ? (i + 1 - nt0) : (i + 1);
      stage_kv(Kg, Vg, Ks[buf ^ 1], Vs[buf ^ 1], w, l, tn * 128);
    }
    int kv0 = ((i >= nt0) ? (i - nt0) : i) * 128;
    if (kv0 <= qw + 31) {
      if (kv0 + 127 > qw) attn_tile<true >(Ks[buf], Vs[buf], qf, oa, lsum, kv0, qg, hi, l31, l7);
      else                attn_tile<false>(Ks[buf], Vs[buf], qf, oa, lsum, kv0, qg, hi, l31, l7);
    }
    if (i == nt0 - 1) {
      attn_writeout(A2, oa, lsum, b, h, qw, hi, l31);
      oa[0] = ZERO; oa[1] = ZERO; lsum = 0.f;
      qw = qt1 * 256 + w * 32;
      qg = qw + l31;
#pragma unroll
      for (int dk = 0; dk < 4; ++dk) qf[dk] = ldbf8(Qg + (size_t)qg * 64 + dk * 16 + hi * 8);
    }
    __syncthreads();
  }
  attn_writeout(A2, oa, lsum, b, h, qw, hi, l31);
}

extern "C" void kernel_launch(void* const* d_in, const int* in_sizes, int n_in,
                              void* d_out, int out_size, void* d_ws, size_t ws_size,
                              hipStream_t stream) {
  const float* x      = (const float*)d_in[0];
  const float* w_attn = (const float*)d_in[1];
  const float* b_attn = (const float*)d_in[2];
  const float* w_proj = (const float*)d_in[3];
  const float* b_proj = (const float*)d_in[4];
  float* out = (float*)d_out;
  char* ws = (char*)d_ws;
  if (ws_size < 92274688u) return;  // need 88 MB scratch
  short* Xb  = (short*)(ws);                 // [8192][1024] bf16
  short* Wta = (short*)(ws + 16777216);      // [3072][1024] bf16 (W^T)
  short* Wtp = (short*)(ws + 23068672);      // [1024][1024] bf16 (W^T)
  short* Qb  = (short*)(ws + 25165824);      // [64 bh][2048][64]
  short* Kb  = (short*)(ws + 41943040);      // [64 bh][2048][64]
  short* VbT = (short*)(ws + 58720256);      // [64 bh][64 d][2048 s]
  short* A2  = (short*)(ws + 75497472);      // [8192][1024] bf16

  hipLaunchKernelGGL(k_cast, dim3(8192), dim3(256), 0, stream, x, Xb);
  hipLaunchKernelGGL(k_transpose, dim3(16, 48), dim3(256), 0, stream, w_attn, Wta, 1024, 3072);
  hipLaunchKernelGGL(k_transpose, dim3(16, 16), dim3(256), 0, stream, w_proj, Wtp, 1024, 1024);
  hipLaunchKernelGGL((k_gemm8<0>), dim3(768), dim3(512), 0, stream, Xb, Wta, b_attn, Qb, Kb, VbT, nullptr);
  hipLaunchKernelGGL(k_attn, dim3(64, 4), dim3(512), 0, stream, Qb, Kb, VbT, A2);
  hipLaunchKernelGGL((k_gemm8<1>), dim3(256), dim3(512), 0, stream, A2, Wtp, b_proj, nullptr, nullptr, nullptr, out);
}

// Round 6
// 166.855 us; speedup vs baseline: 1.1479x; 1.0682x over previous
//
#include <hip/hip_runtime.h>
#include <cstdint>
#include <cstddef>

// GPT-2 attention block: qkv = x@Wa + ba ; causal softmax(QK^T) V ; out = a@Wp + bp
// B=4 S=2048 D=1024 H=16 hd=64. All matmuls in bf16 MFMA (fp32 accum).

using f32x4  = __attribute__((ext_vector_type(4))) float;
using f32x16 = __attribute__((ext_vector_type(16))) float;
using bf8    = __attribute__((ext_vector_type(8))) __bf16;

static __device__ __forceinline__ short f2bf(float f) {
  union { float f; unsigned u; } v; v.f = f;
  unsigned r = v.u + 0x7fffu + ((v.u >> 16) & 1u);  // RNE
  return (short)(r >> 16);
}

static __device__ __forceinline__ bf8 ldbf8(const short* p) { return *(const bf8*)p; }

static __device__ __forceinline__ f32x4 mfma16(bf8 a, bf8 b, f32x4 c) {
  return __builtin_amdgcn_mfma_f32_16x16x32_bf16(a, b, c, 0, 0, 0);
}
static __device__ __forceinline__ f32x16 mfma32(bf8 a, bf8 b, f32x16 c) {
  return __builtin_amdgcn_mfma_f32_32x32x16_bf16(a, b, c, 0, 0, 0);
}

static __device__ __forceinline__ void gload16(const void* g, void* l) {
  __builtin_amdgcn_global_load_lds((const __attribute__((address_space(1))) void*)g,
                                   (__attribute__((address_space(3))) void*)l, 16, 0, 0);
}

static __device__ __forceinline__ unsigned cvtpk(float a, float b) {
  unsigned r;
  asm("v_cvt_pk_bf16_f32 %0, %1, %2" : "=v"(r) : "v"(a), "v"(b));
  return r;
}
static __device__ __forceinline__ void permswap(unsigned& a, unsigned& b) {
  asm("v_permlane32_swap_b32 %0, %1" : "+v"(a), "+v"(b));
}

// vmcnt(N) + raw barrier + compiler memory fence (k_gemm8 legacy macro)
#define KWAIT(N) do { asm volatile("s_waitcnt vmcnt(" #N ")" ::: "memory"); \
    __builtin_amdgcn_s_barrier(); asm volatile("" ::: "memory"); } while (0)

#define PHASE_SYNC() do { \
    asm volatile("" ::: "memory"); \
    __builtin_amdgcn_s_barrier(); \
    asm volatile("s_waitcnt lgkmcnt(0)" ::: "memory"); \
    __builtin_amdgcn_sched_barrier(0); } while (0)

// ---------------- cast x (fp32) -> bf16 ----------------
__global__ __launch_bounds__(256) void k_cast(const float* __restrict__ in, short* __restrict__ out) {
  int i = blockIdx.x * 256 + threadIdx.x;
  float4 v = ((const float4*)in)[i];
  short4 o; o.x = f2bf(v.x); o.y = f2bf(v.y); o.z = f2bf(v.z); o.w = f2bf(v.w);
  ((short4*)out)[i] = o;
}

// ---------------- W[K][N] fp32 -> Wt[N][K] bf16 ----------------
__global__ __launch_bounds__(256) void k_transpose(const float* __restrict__ W, short* __restrict__ Wt,
                                                   int K, int N) {
  __shared__ short Ls[64][66];
  int k0 = blockIdx.x * 64, n0 = blockIdx.y * 64;
  int t = threadIdx.x;
#pragma unroll
  for (int p = 0; p < 16; ++p) {
    int idx = p * 256 + t;
    int kk = idx >> 6, nn = idx & 63;
    Ls[kk][nn] = f2bf(W[(size_t)(k0 + kk) * N + n0 + nn]);
  }
  __syncthreads();
#pragma unroll
  for (int p = 0; p < 16; ++p) {
    int idx = p * 256 + t;
    int nn = idx >> 6, kk = idx & 63;
    Wt[(size_t)(n0 + nn) * K + k0 + kk] = Ls[kk][nn];
  }
}

// ---------------- QKV GEMM v9: 256x256 tile, BK=64, 8-phase counted-vmcnt pipeline ----------
// A=Xb[8192][1024], B=Wta[3072][1024] (both [row][K] bf16). 8 waves 2Mx4N, per-wave C=128x64.
// LDS: As/Bs [2 buf][2 half][128x64], chunk-XOR swizzle slot=c^(row&7) via pre-swizzled source.
// Stage schedule per tile T: P1->T+1.A1, P2->T+1.B1, P3->T+2.A0, P4->T+2.B0, vmcnt(4)@P4.
__global__ __launch_bounds__(512, 2) void k_gemm9(const short* __restrict__ Ag, const short* __restrict__ Bg,
                                                  const float* __restrict__ bias,
                                                  short* __restrict__ Qb, short* __restrict__ Kb,
                                                  short* __restrict__ VbT) {
  __shared__ __align__(16) short As[2][2][128 * 64];
  __shared__ __align__(16) short Bs[2][2][128 * 64];
  const int NTN = 12, NWG = 384;
  int bid = blockIdx.x;
  int wg = (bid & 7) * (NWG >> 3) + (bid >> 3);   // bijective XCD swizzle
  int m0 = (wg / NTN) * 256, n0 = (wg % NTN) * 256;
  int t = threadIdx.x, w = t >> 6, l = t & 63;
  int wm = w >> 2, wn = w & 3;
  int lg = l >> 4, l15 = l & 15;

  // fragment ds-read offsets (in shorts, within one [128][64] half)
  int aoffq[4][2], boffj[2][2];
#pragma unroll
  for (int q = 0; q < 4; ++q)
#pragma unroll
    for (int ks = 0; ks < 2; ++ks) {
      int rr = wm * 64 + q * 16 + l15;
      aoffq[q][ks] = rr * 64 + (((ks * 4 + lg) ^ (rr & 7)) * 8);
    }
#pragma unroll
  for (int j = 0; j < 2; ++j)
#pragma unroll
    for (int ks = 0; ks < 2; ++ks) {
      int rr = wn * 32 + j * 16 + l15;
      boffj[j][ks] = rr * 64 + (((ks * 4 + lg) ^ (rr & 7)) * 8);
    }

  auto stgA = [&](int kt, int half, int buf) {
#pragma unroll
    for (int u = 0; u < 2; ++u) {
      int srw = u * 64 + w * 8 + (l >> 3);
      gload16(Ag + (size_t)(m0 + half * 128 + srw) * 1024 + kt * 64 + (((l & 7) ^ (srw & 7)) * 8),
              &As[buf][half][(u * 64 + w * 8) * 64]);
    }
  };
  auto stgB = [&](int kt, int half, int buf) {
#pragma unroll
    for (int u = 0; u < 2; ++u) {
      int srw = u * 64 + w * 8 + (l >> 3);
      gload16(Bg + (size_t)(n0 + half * 128 + srw) * 1024 + kt * 64 + (((l & 7) ^ (srw & 7)) * 8),
              &Bs[buf][half][(u * 64 + w * 8) * 64]);
    }
  };

  f32x4 acc[8][4] = {};

  // prologue: T0 full (8 loads) + T1.A0,B0 (4 loads); vmcnt(4) => T0 landed
  stgA(0, 0, 0); stgA(0, 1, 0); stgB(0, 0, 0); stgB(0, 1, 0);
  stgA(1, 0, 1); stgB(1, 0, 1);
  asm volatile("s_waitcnt vmcnt(4)" ::: "memory");
  __builtin_amdgcn_s_barrier();

  bf8 aq[4][2], bp0[2][2], bp1[2][2];
  for (int kt = 0; kt < 16; ++kt) {
    int buf = kt & 1, nb = buf ^ 1;
    // ---- P1: read A-quad0 + B-pair0 ; stage T+1.A1 ; MFMA Q(0,0)
#pragma unroll
    for (int q = 0; q < 4; ++q)
#pragma unroll
      for (int ks = 0; ks < 2; ++ks) aq[q][ks] = ldbf8(&As[buf][0][aoffq[q][ks]]);
#pragma unroll
    for (int j = 0; j < 2; ++j)
#pragma unroll
      for (int ks = 0; ks < 2; ++ks) bp0[j][ks] = ldbf8(&Bs[buf][0][boffj[j][ks]]);
    asm volatile("" ::: "memory");
    if (kt + 1 < 16) stgA(kt + 1, 1, nb);
    PHASE_SYNC();
    __builtin_amdgcn_s_setprio(1);
#pragma unroll
    for (int q = 0; q < 4; ++q)
#pragma unroll
      for (int j = 0; j < 2; ++j) {
        acc[q][j] = mfma16(aq[q][0], bp0[j][0], acc[q][j]);
        acc[q][j] = mfma16(aq[q][1], bp0[j][1], acc[q][j]);
      }
    __builtin_amdgcn_s_setprio(0);
    __builtin_amdgcn_s_barrier();
    // ---- P2: read B-pair1 ; stage T+1.B1 ; MFMA Q(0,1)
#pragma unroll
    for (int j = 0; j < 2; ++j)
#pragma unroll
      for (int ks = 0; ks < 2; ++ks) bp1[j][ks] = ldbf8(&Bs[buf][1][boffj[j][ks]]);
    asm volatile("" ::: "memory");
    if (kt + 1 < 16) stgB(kt + 1, 1, nb);
    PHASE_SYNC();
    __builtin_amdgcn_s_setprio(1);
#pragma unroll
    for (int q = 0; q < 4; ++q)
#pragma unroll
      for (int j = 0; j < 2; ++j) {
        acc[q][2 + j] = mfma16(aq[q][0], bp1[j][0], acc[q][2 + j]);
        acc[q][2 + j] = mfma16(aq[q][1], bp1[j][1], acc[q][2 + j]);
      }
    __builtin_amdgcn_s_setprio(0);
    __builtin_amdgcn_s_barrier();
    // ---- P3: read A-quad1 ; stage T+2.A0 ; MFMA Q(1,0)
#pragma unroll
    for (int q = 0; q < 4; ++q)
#pragma unroll
      for (int ks = 0; ks < 2; ++ks) aq[q][ks] = ldbf8(&As[buf][1][aoffq[q][ks]]);
    asm volatile("" ::: "memory");
    if (kt + 2 < 16) stgA(kt + 2, 0, buf);
    PHASE_SYNC();
    __builtin_amdgcn_s_setprio(1);
#pragma unroll
    for (int q = 0; q < 4; ++q)
#pragma unroll
      for (int j = 0; j < 2; ++j) {
        acc[4 + q][j] = mfma16(aq[q][0], bp0[j][0], acc[4 + q][j]);
        acc[4 + q][j] = mfma16(aq[q][1], bp0[j][1], acc[4 + q][j]);
      }
    __builtin_amdgcn_s_setprio(0);
    __builtin_amdgcn_s_barrier();
    // ---- P4: no ds-reads ; stage T+2.B0 ; vmcnt ; MFMA Q(1,1)
    if (kt + 2 < 16) stgB(kt + 2, 0, buf);
    if (kt == 14) { asm volatile("s_waitcnt vmcnt(0)" ::: "memory"); }
    else          { asm volatile("s_waitcnt vmcnt(4)" ::: "memory"); }
    __builtin_amdgcn_s_barrier();
    __builtin_amdgcn_s_setprio(1);
#pragma unroll
    for (int q = 0; q < 4; ++q)
#pragma unroll
      for (int j = 0; j < 2; ++j) {
        acc[4 + q][2 + j] = mfma16(aq[q][0], bp1[j][0], acc[4 + q][2 + j]);
        acc[4 + q][2 + j] = mfma16(aq[q][1], bp1[j][1], acc[4 + q][2 + j]);
      }
    __builtin_amdgcn_s_setprio(0);
    __builtin_amdgcn_s_barrier();
  }

  // epilogue: scatter Q/K [bh][s][64], V^T [bh][64][2048]
  float bv[4];
#pragma unroll
  for (int nj = 0; nj < 4; ++nj)
    bv[nj] = bias[n0 + (nj >> 1) * 128 + wn * 32 + (nj & 1) * 16 + l15];
#pragma unroll
  for (int mi = 0; mi < 8; ++mi) {
    int gr0 = m0 + (mi >> 2) * 128 + wm * 64 + (mi & 3) * 16 + lg * 4;
    int bq = gr0 >> 11, s0 = gr0 & 2047;
#pragma unroll
    for (int nj = 0; nj < 4; ++nj) {
      int gc = n0 + (nj >> 1) * 128 + wn * 32 + (nj & 1) * 16 + l15;
      int which = gc >> 10, rem = gc & 1023;
      int hh = rem >> 6, dd = rem & 63;
      if (which == 2) {
        short4 pk;
        pk.x = f2bf(acc[mi][nj][0] + bv[nj]);
        pk.y = f2bf(acc[mi][nj][1] + bv[nj]);
        pk.z = f2bf(acc[mi][nj][2] + bv[nj]);
        pk.w = f2bf(acc[mi][nj][3] + bv[nj]);
        *(short4*)&VbT[((size_t)((bq * 16 + hh) * 64 + dd)) * 2048 + s0] = pk;
      } else {
        short* dst = which == 0 ? Qb : Kb;
#pragma unroll
        for (int r = 0; r < 4; ++r)
          dst[((size_t)((bq * 16 + hh) * 2048 + (s0 + r))) * 64 + dd] = f2bf(acc[mi][nj][r] + bv[nj]);
      }
    }
  }
}

// ---------------- GEMM v8 (proj): BM=256 BN=128 BK=64, 2 bufs, 1 barrier/tile ----
static __device__ __forceinline__ void gemm8_compute(const short* __restrict__ Ab,
                                                     const short* __restrict__ Bb,
                                                     const int (&aoff)[8][2], const int (&boff)[2][2],
                                                     f32x4 (&acc)[8][2]) {
  bf8 bfr[2][2];
#pragma unroll
  for (int j = 0; j < 2; ++j)
#pragma unroll
    for (int ks = 0; ks < 2; ++ks)
      bfr[j][ks] = ldbf8(Bb + boff[j][ks]);
#pragma unroll
  for (int mi = 0; mi < 8; ++mi) {
    bf8 a0 = ldbf8(Ab + aoff[mi][0]);
    bf8 a1 = ldbf8(Ab + aoff[mi][1]);
    __builtin_amdgcn_s_setprio(1);
    acc[mi][0] = mfma16(a0, bfr[0][0], acc[mi][0]);
    acc[mi][0] = mfma16(a1, bfr[0][1], acc[mi][0]);
    acc[mi][1] = mfma16(a0, bfr[1][0], acc[mi][1]);
    acc[mi][1] = mfma16(a1, bfr[1][1], acc[mi][1]);
    __builtin_amdgcn_s_setprio(0);
  }
}

__global__ __launch_bounds__(512, 2) void k_gemm8p(const short* __restrict__ Ag, const short* __restrict__ Bg,
                                                   const float* __restrict__ bias, float* __restrict__ Out) {
  constexpr int NTN = 8;
  constexpr int NWG = 32 * NTN;
  __shared__ __align__(16) short As[2][256 * 64];
  __shared__ __align__(16) short Bs[2][128 * 64];
  int bid = blockIdx.x;
  int wg = (bid & 7) * (NWG >> 3) + (bid >> 3);
  int m0 = (wg / NTN) * 256, n0 = (wg % NTN) * 128;
  int t = threadIdx.x, w = t >> 6, l = t & 63;
  int wm = w >> 2, wn = w & 3;
  int srow = w * 8 + (l >> 3);
  int sswz = ((l & 7) ^ (srow & 7)) * 8;
  const short* aSrc = Ag + (size_t)(m0 + srow) * 1024 + sswz;
  const short* bSrc = Bg + (size_t)(n0 + srow) * 1024 + sswz;
  int aoff[8][2], boff[2][2];
#pragma unroll
  for (int mi = 0; mi < 8; ++mi)
#pragma unroll
    for (int ks = 0; ks < 2; ++ks) {
      int rr = wm * 128 + mi * 16 + (l & 15);
      aoff[mi][ks] = rr * 64 + (((ks * 4 + (l >> 4)) ^ (rr & 7)) * 8);
    }
#pragma unroll
  for (int j = 0; j < 2; ++j)
#pragma unroll
    for (int ks = 0; ks < 2; ++ks) {
      int rr = wn * 32 + j * 16 + (l & 15);
      boff[j][ks] = rr * 64 + (((ks * 4 + (l >> 4)) ^ (rr & 7)) * 8);
    }
  f32x4 acc[8][2] = {};

#define STAGE8(kt, bf) do { \
    _Pragma("unroll") for (int g = 0; g < 4; ++g) \
      gload16(aSrc + (size_t)g * 65536 + (kt) * 64, &As[bf][g * 4096 + w * 512]); \
    _Pragma("unroll") for (int g = 0; g < 2; ++g) \
      gload16(bSrc + (size_t)g * 65536 + (kt) * 64, &Bs[bf][g * 4096 + w * 512]); \
  } while (0)

  STAGE8(0, 0);
  KWAIT(0);
  for (int kt = 0; kt < 15; ++kt) {
    STAGE8(kt + 1, (kt + 1) & 1);
    gemm8_compute(As[kt & 1], Bs[kt & 1], aoff, boff, acc);
    KWAIT(0);
  }
  gemm8_compute(As[1], Bs[1], aoff, boff, acc);
#undef STAGE8

  float bv[2];
#pragma unroll
  for (int nj = 0; nj < 2; ++nj) bv[nj] = bias[n0 + wn * 32 + nj * 16 + (l & 15)];
#pragma unroll
  for (int mi = 0; mi < 8; ++mi) {
    int gr0 = m0 + wm * 128 + mi * 16 + (l >> 4) * 4;
#pragma unroll
    for (int nj = 0; nj < 2; ++nj) {
      int gc = n0 + wn * 32 + nj * 16 + (l & 15);
#pragma unroll
      for (int r = 0; r < 4; ++r)
        Out[(size_t)(gr0 + r) * 1024 + gc] = acc[mi][nj][r] + bv[nj];
    }
  }
}

// ---------------- Flash attention v3: swapped 32x32 MFMA, in-register P ----------------
static __device__ __forceinline__ void stage_kv(const short* __restrict__ Kg, const short* __restrict__ Vg,
                                                short* KsB, short* VsB, int w, int l, int kv0) {
#pragma unroll
  for (int i = 0; i < 2; ++i) {
    int k = i * 64 + w * 8 + (l >> 3);
    int c = (l & 7) ^ (k & 7);
    gload16(Kg + (size_t)(kv0 + k) * 64 + c * 8, KsB + i * 4096 + w * 512);
  }
#pragma unroll
  for (int i = 0; i < 2; ++i) {
    int d = i * 32 + w * 4 + (l >> 4);
    int s = l & 15;
    int c = (s & 8) | ((s & 7) ^ (d & 7));
    gload16(Vg + (size_t)d * 2048 + kv0 + c * 8, VsB + i * 4096 + w * 512);
  }
}

template <bool MASK>
static __device__ __forceinline__ void attn_tile(const short* __restrict__ KsB, const short* __restrict__ VsB,
                                                 const bf8* qf, f32x16* oa, float& lsum,
                                                 int kv0, int qg, int hi, int l31, int l7) {
  bf8 pfr[8];
#pragma unroll
  for (int kb = 0; kb < 4; ++kb) {
    f32x16 sv = {};
#pragma unroll
    for (int dk = 0; dk < 4; ++dk) {
      bf8 kf = ldbf8(&KsB[(32 * kb + l31) * 64 + (((2 * dk + hi) ^ l7) * 8)]);
      sv = mfma32(kf, qf[dk], sv);
    }
    float pe[16];
#pragma unroll
    for (int r = 0; r < 16; ++r) {
      float e = __expf(sv[r]);
      if constexpr (MASK) {
        int kg = kv0 + 32 * kb + ((r & 3) + 8 * (r >> 2) + 4 * hi);
        e = (kg > qg) ? 0.f : e;
      }
      pe[r] = e;
      lsum += e;
    }
#pragma unroll
    for (int rh = 0; rh < 2; ++rh) {
      unsigned a01 = cvtpk(pe[8 * rh + 0], pe[8 * rh + 1]);
      unsigned a23 = cvtpk(pe[8 * rh + 2], pe[8 * rh + 3]);
      unsigned b01 = cvtpk(pe[8 * rh + 4], pe[8 * rh + 5]);
      unsigned b23 = cvtpk(pe[8 * rh + 6], pe[8 * rh + 7]);
      permswap(a01, b01);
      permswap(a23, b23);
      union { unsigned u[4]; bf8 v; } fu;
      fu.u[0] = a01; fu.u[1] = a23; fu.u[2] = b01; fu.u[3] = b23;
      pfr[2 * kb + rh] = fu.v;
    }
  }
#pragma unroll
  for (int db = 0; db < 2; ++db) {
#pragma unroll
    for (int ks = 0; ks < 8; ++ks) {
      int c = 2 * ks + hi;
      bf8 vf = ldbf8(&VsB[(32 * db + l31) * 128 + (((c & 8) | ((c & 7) ^ l7)) * 8)]);
      oa[db] = mfma32(pfr[ks], vf, oa[db]);
    }
  }
}

static __device__ __forceinline__ void attn_writeout(short* __restrict__ A2, const f32x16* oa, float lsum,
                                                     int b, int h, int qw, int hi, int l31) {
  float lf = lsum + __shfl_xor(lsum, 32, 64);
#pragma unroll
  for (int r = 0; r < 16; ++r) {
    int cr = (r & 3) + 8 * (r >> 2) + 4 * hi;
    float li = __shfl(lf, cr, 64);
    float ri = 1.0f / li;
    size_t row = (size_t)(b * 2048 + qw + cr) * 1024 + h * 64 + l31;
#pragma unroll
    for (int db = 0; db < 2; ++db)
      A2[row + 32 * db] = f2bf(oa[db][r] * ri);
  }
}

__global__ __launch_bounds__(512) void k_attn(const short* __restrict__ Q, const short* __restrict__ K,
                                              const short* __restrict__ VT, short* __restrict__ A2) {
  __shared__ __align__(16) short Ks[2][128 * 64];
  __shared__ __align__(16) short Vs[2][64 * 128];
  int bh = blockIdx.x;
  int pr = blockIdx.y;                // 0..3, processes q-tiles (pr, 7-pr): constant 18 KV tiles
  int b = bh >> 4, h = bh & 15;
  int t = threadIdx.x, w = t >> 6, l = t & 63;
  int hi = l >> 5, l31 = l & 31, l7 = l & 7;
  const short* Qg = Q + (size_t)bh * 2048 * 64;
  const short* Kg = K + (size_t)bh * 2048 * 64;
  const short* Vg = VT + (size_t)bh * 64 * 2048;

  int qt0 = pr, qt1 = 7 - pr;
  int nt0 = 2 * (qt0 + 1);
  int total = nt0 + 2 * (qt1 + 1);

  const f32x16 ZERO = {};
  f32x16 oa[2] = {};
  float lsum = 0.f;

  int qw = qt0 * 256 + w * 32;
  int qg = qw + l31;
  bf8 qf[4];
#pragma unroll
  for (int dk = 0; dk < 4; ++dk) qf[dk] = ldbf8(Qg + (size_t)qg * 64 + dk * 16 + hi * 8);

  stage_kv(Kg, Vg, Ks[0], Vs[0], w, l, 0);
  __syncthreads();

  for (int i = 0; i < total; ++i) {
    int buf = i & 1;
    if (i + 1 < total) {
      int tn = (i + 1 >= nt0) ? (i + 1 - nt0) : (i + 1);
      stage_kv(Kg, Vg, Ks[buf ^ 1], Vs[buf ^ 1], w, l, tn * 128);
    }
    int kv0 = ((i >= nt0) ? (i - nt0) : i) * 128;
    if (kv0 <= qw + 31) {
      if (kv0 + 127 > qw) attn_tile<true >(Ks[buf], Vs[buf], qf, oa, lsum, kv0, qg, hi, l31, l7);
      else                attn_tile<false>(Ks[buf], Vs[buf], qf, oa, lsum, kv0, qg, hi, l31, l7);
    }
    if (i == nt0 - 1) {
      attn_writeout(A2, oa, lsum, b, h, qw, hi, l31);
      oa[0] = ZERO; oa[1] = ZERO; lsum = 0.f;
      qw = qt1 * 256 + w * 32;
      qg = qw + l31;
#pragma unroll
      for (int dk = 0; dk < 4; ++dk) qf[dk] = ldbf8(Qg + (size_t)qg * 64 + dk * 16 + hi * 8);
    }
    __syncthreads();
  }
  attn_writeout(A2, oa, lsum, b, h, qw, hi, l31);
}

extern "C" void kernel_launch(void* const* d_in, const int* in_sizes, int n_in,
                              void* d_out, int out_size, void* d_ws, size_t ws_size,
                              hipStream_t stream) {
  const float* x      = (const float*)d_in[0];
  const float* w_attn = (const float*)d_in[1];
  const float* b_attn = (const float*)d_in[2];
  const float* w_proj = (const float*)d_in[3];
  const float* b_proj = (const float*)d_in[4];
  float* out = (float*)d_out;
  char* ws = (char*)d_ws;
  if (ws_size < 92274688u) return;  // need 88 MB scratch
  short* Xb  = (short*)(ws);                 // [8192][1024] bf16
  short* Wta = (short*)(ws + 16777216);      // [3072][1024] bf16 (W^T)
  short* Wtp = (short*)(ws + 23068672);      // [1024][1024] bf16 (W^T)
  short* Qb  = (short*)(ws + 25165824);      // [64 bh][2048][64]
  short* Kb  = (short*)(ws + 41943040);      // [64 bh][2048][64]
  short* VbT = (short*)(ws + 58720256);      // [64 bh][64 d][2048 s]
  short* A2  = (short*)(ws + 75497472);      // [8192][1024] bf16

  hipLaunchKernelGGL(k_cast, dim3(8192), dim3(256), 0, stream, x, Xb);
  hipLaunchKernelGGL(k_transpose, dim3(16, 48), dim3(256), 0, stream, w_attn, Wta, 1024, 3072);
  hipLaunchKernelGGL(k_transpose, dim3(16, 16), dim3(256), 0, stream, w_proj, Wtp, 1024, 1024);
  hipLaunchKernelGGL(k_gemm9, dim3(384), dim3(512), 0, stream, Xb, Wta, b_attn, Qb, Kb, VbT);
  hipLaunchKernelGGL(k_attn, dim3(64, 4), dim3(512), 0, stream, Qb, Kb, VbT, A2);
  hipLaunchKernelGGL(k_gemm8p, dim3(256), dim3(512), 0, stream, A2, Wtp, b_proj, out);
}